// Round 5
// baseline (881.460 us; speedup 1.0000x reference)
//
#include <hip/hip_runtime.h>

#define NN 100000
#define NE 1600000
#define BN_EPS 1e-5f
#define NBKT 1024
#define BNODE 98          // nodes per bucket: 1024*98 = 100352 >= NN
#define LSTR 68           // LDS agg row stride (floats): 16B-aligned, bank-spread
#define NBLK 400          // binning blocks
#define CHUNK 4000        // edges per binning block (400*4000 = NE)

typedef short s8v __attribute__((ext_vector_type(8)));
typedef float f4v __attribute__((ext_vector_type(4)));

__device__ __forceinline__ float bf2f(unsigned short u) {
  union { unsigned u; float f; } v; v.u = ((unsigned)u) << 16; return v.f;
}
__device__ __forceinline__ unsigned short f2bf(float f) {
  union { float f; unsigned u; } v; v.f = f;
  return (unsigned short)((v.u + 0x7FFFu + ((v.u >> 16) & 1u)) >> 16);
}

#define MFMA16(a, b, c) __builtin_amdgcn_mfma_f32_16x16x32_bf16((a), (b), (c), 0, 0, 0)

// ---------------------------------------------------------------------------
// Pre-GEMM: F = X @ W1[0:64,:], G = X @ W1[64:128,:]  (bf16 [NN][64])
// ---------------------------------------------------------------------------
__global__ __launch_bounds__(256) void pre_gemm_kernel(
    const float* __restrict__ x, const float* __restrict__ W1,
    unsigned short* __restrict__ F, unsigned short* __restrict__ G)
{
  const int lane = threadIdx.x & 63;
  const int wv   = threadIdx.x >> 6;
  const int q    = lane >> 4;
  const int r    = lane & 15;
  const int nw   = gridDim.x * 4;
  const int wid  = blockIdx.x * 4 + wv;

  s8v Bt[2][4], Bb[2][4];
#pragma unroll
  for (int kk = 0; kk < 2; ++kk)
#pragma unroll
    for (int nt = 0; nt < 4; ++nt) {
      s8v ft, fb;
#pragma unroll
      for (int j = 0; j < 8; ++j) {
        ft[j] = (short)f2bf(W1[(kk * 32 + q * 8 + j) * 64 + nt * 16 + r]);
        fb[j] = (short)f2bf(W1[(64 + kk * 32 + q * 8 + j) * 64 + nt * 16 + r]);
      }
      Bt[kk][nt] = ft; Bb[kk][nt] = fb;
    }

  for (int t = wid; t < NN / 16; t += nw) {
    const int n = t * 16 + r;
    const f4v* xp = (const f4v*)(x + (size_t)n * 64);
    f4v x0 = xp[q * 2],     x1 = xp[q * 2 + 1];
    f4v x2 = xp[8 + q * 2], x3 = xp[8 + q * 2 + 1];
    s8v a0, a1v;
#pragma unroll
    for (int j = 0; j < 4; ++j) {
      a0[j]      = (short)f2bf(x0[j]);
      a0[4 + j]  = (short)f2bf(x1[j]);
      a1v[j]     = (short)f2bf(x2[j]);
      a1v[4 + j] = (short)f2bf(x3[j]);
    }
    f4v aF[4], aG[4];
#pragma unroll
    for (int nt = 0; nt < 4; ++nt) {
      f4v c = {0.f, 0.f, 0.f, 0.f};
      c = MFMA16(a0,  Bt[0][nt], c);
      c = MFMA16(a1v, Bt[1][nt], c);
      aF[nt] = c;
      f4v d = {0.f, 0.f, 0.f, 0.f};
      d = MFMA16(a0,  Bb[0][nt], d);
      d = MFMA16(a1v, Bb[1][nt], d);
      aG[nt] = d;
    }
#pragma unroll
    for (int nt = 0; nt < 4; ++nt)
#pragma unroll
      for (int rg = 0; rg < 4; ++rg) {
        const size_t idx = (size_t)(t * 16 + q * 4 + rg) * 64 + nt * 16 + r;
        F[idx] = f2bf(aF[nt][rg]);
        G[idx] = f2bf(aG[nt][rg]);
      }
  }
}

// ---------------------------------------------------------------------------
// Binning pass 1: per-block LDS histogram over 1024 buckets -> hmat[blk][1024]
// ---------------------------------------------------------------------------
__global__ __launch_bounds__(256) void hist_kernel(
    const int* __restrict__ dstp, int* __restrict__ hmat)
{
  __shared__ int lh[NBKT];
  const int t = threadIdx.x;
#pragma unroll
  for (int j = 0; j < 4; ++j) lh[t + j * 256] = 0;
  __syncthreads();
  const int base = blockIdx.x * CHUNK;
#pragma unroll
  for (int i = 0; i < 16; ++i) {
    const int o = i * 256 + t;
    if (o < CHUNK) {
      const int d = dstp[base + o];
      atomicAdd(&lh[d / BNODE], 1);
    }
  }
  __syncthreads();
#pragma unroll
  for (int j = 0; j < 4; ++j) {
    const int bb = t + j * 256;
    hmat[blockIdx.x * NBKT + bb] = lh[bb];
  }
}

// ---------------------------------------------------------------------------
// Binning pass 2a: per-bucket column exclusive scan over blocks; total[b]
// ---------------------------------------------------------------------------
__global__ __launch_bounds__(256) void scan_col_kernel(
    int* __restrict__ hmat, int* __restrict__ total)
{
  const int b = blockIdx.x * 256 + threadIdx.x;   // 4 blocks x 256 = 1024
  int run = 0;
#pragma unroll 4
  for (int blk = 0; blk < NBLK; ++blk) {
    const int idx = blk * NBKT + b;
    const int v = hmat[idx];
    hmat[idx] = run;
    run += v;
  }
  total[b] = run;
}

// ---------------------------------------------------------------------------
// Binning pass 2b: exclusive scan of total[1024] -> boffs[1025]
// ---------------------------------------------------------------------------
__global__ void scan_total_kernel(const int* __restrict__ total, int* __restrict__ boffs)
{
  const int tid = threadIdx.x;                    // 1 block x 256
  const int lane = tid & 63, wv = tid >> 6;
  __shared__ int wsum[4], wbase[4];
  int v[4]; int s = 0;
#pragma unroll
  for (int j = 0; j < 4; ++j) { v[j] = total[tid * 4 + j]; s += v[j]; }
  int inc = s;
#pragma unroll
  for (int d = 1; d < 64; d <<= 1) { int t = __shfl_up(inc, d, 64); if (lane >= d) inc += t; }
  if (lane == 63) wsum[wv] = inc;
  __syncthreads();
  if (tid == 0) { int run = 0; for (int k = 0; k < 4; ++k) { wbase[k] = run; run += wsum[k]; } }
  __syncthreads();
  int run = wbase[wv] + inc - s;
#pragma unroll
  for (int j = 0; j < 4; ++j) { boffs[tid * 4 + j] = run; run += v[j]; }
  if (tid == 0) boffs[NBKT] = NE;
}

// ---------------------------------------------------------------------------
// Binning pass 3: scatter edges into bucket-ordered ebuf; LDS cursors only.
// encode: word = (src << 7) | (dst - bucket*98)   (dloc < 98 < 128)
// ---------------------------------------------------------------------------
__global__ __launch_bounds__(256) void scatter_kernel(
    const int* __restrict__ srcp, const int* __restrict__ dstp,
    const int* __restrict__ hmat, const int* __restrict__ boffs,
    int* __restrict__ ebuf)
{
  __shared__ int lcur[NBKT];
  const int t = threadIdx.x;
#pragma unroll
  for (int j = 0; j < 4; ++j) {
    const int bb = t + j * 256;
    lcur[bb] = boffs[bb] + hmat[blockIdx.x * NBKT + bb];
  }
  __syncthreads();
  const int base = blockIdx.x * CHUNK;
#pragma unroll
  for (int i = 0; i < 16; ++i) {
    const int o = i * 256 + t;
    if (o < CHUNK) {
      const int d = dstp[base + o];
      const int s = srcp[base + o];
      const int b = d / BNODE;
      const int p = atomicAdd(&lcur[b], 1);
      ebuf[p] = (s << 7) | (d - b * BNODE);
    }
  }
}

// ---------------------------------------------------------------------------
// Edge MLP + aggregation: one workgroup per bucket; agg tile lives in LDS;
// per-edge h2 = prelu(prelu(F[dst]+G[src]+b1) @ W2 + b2) added via LDS atomics;
// one plain-store flush per node. ZERO global atomics.
// ---------------------------------------------------------------------------
__global__ __launch_bounds__(256) void edge_agg_kernel(
    const unsigned short* __restrict__ F, const unsigned short* __restrict__ G,
    const int* __restrict__ ebuf, const int* __restrict__ boffs,
    const float* __restrict__ b1, const float* __restrict__ a1p,
    const float* __restrict__ W2, const float* __restrict__ b2,
    const float* __restrict__ a2p,
    float* __restrict__ agg)
{
  __shared__ __align__(16) float sagg[BNODE * LSTR];   // 26,656 B
  const int tid  = threadIdx.x;
  const int lane = tid & 63;
  const int wv   = tid >> 6;
  const int q    = lane >> 4;
  const int r    = lane & 15;

  for (int i = tid; i < BNODE * LSTR; i += 256) sagg[i] = 0.f;

  s8v B2f[2][4];
#pragma unroll
  for (int kk = 0; kk < 2; ++kk)
#pragma unroll
    for (int nt = 0; nt < 4; ++nt) {
      s8v f;
#pragma unroll
      for (int j = 0; j < 8; ++j)
        f[j] = (short)f2bf(W2[(kk * 32 + q * 8 + j) * 64 + nt * 16 + r]);
      B2f[kk][nt] = f;
    }

  float b1f[16];
#pragma unroll
  for (int j = 0; j < 8; ++j) {
    b1f[j]     = b1[q * 8 + j];
    b1f[8 + j] = b1[32 + q * 8 + j];
  }
  float bias2[4];
#pragma unroll
  for (int nt = 0; nt < 4; ++nt) bias2[nt] = b2[nt * 16 + r];
  const float al1 = a1p[0];
  const float al2 = a2p[0];

  const int bkt   = blockIdx.x;
  const int node0 = bkt * BNODE;
  const int start = boffs[bkt], end = boffs[bkt + 1];

  __syncthreads();   // LDS zero visible before any ds_add

  for (int e0 = start + wv * 16; e0 < end; e0 += 64) {
    const int e  = e0 + r;
    const int ec = e < end ? e : end - 1;
    const int w  = ebuf[ec];
    const int dloc = w & 127;
    const int sn   = w >> 7;
    const int dn   = node0 + dloc;

    s8v fa = *(const s8v*)(F + (size_t)dn * 64 + q * 8);
    s8v fb = *(const s8v*)(F + (size_t)dn * 64 + 32 + q * 8);
    s8v ga = *(const s8v*)(G + (size_t)sn * 64 + q * 8);
    s8v gb = *(const s8v*)(G + (size_t)sn * 64 + 32 + q * 8);

    s8v p0, p1;
#pragma unroll
    for (int j = 0; j < 8; ++j) {
      float v = bf2f((unsigned short)fa[j]) + bf2f((unsigned short)ga[j]) + b1f[j];
      v = v >= 0.f ? v : al1 * v;
      p0[j] = (short)f2bf(v);
      float u = bf2f((unsigned short)fb[j]) + bf2f((unsigned short)gb[j]) + b1f[8 + j];
      u = u >= 0.f ? u : al1 * u;
      p1[j] = (short)f2bf(u);
    }

    f4v acc2[4];
#pragma unroll
    for (int nt = 0; nt < 4; ++nt) {
      f4v c = {0.f, 0.f, 0.f, 0.f};
      c = MFMA16(p0, B2f[0][nt], c);
      c = MFMA16(p1, B2f[1][nt], c);
      acc2[nt] = c;
    }

    int drl[4];
#pragma unroll
    for (int rg = 0; rg < 4; ++rg) drl[rg] = __shfl(dloc, q * 4 + rg, 64);

#pragma unroll
    for (int nt = 0; nt < 4; ++nt)
#pragma unroll
      for (int rg = 0; rg < 4; ++rg) {
        float v = acc2[nt][rg] + bias2[nt];
        v = v >= 0.f ? v : al2 * v;
        if (e0 + q * 4 + rg < end)
          atomicAdd(&sagg[drl[rg] * LSTR + nt * 16 + r], v);
      }
  }

  __syncthreads();

  for (int i = tid; i < BNODE * 16; i += 256) {
    const int row = i >> 4, c4 = i & 15;
    const int g = node0 + row;
    if (g < NN) {
      f4v vv = *(const f4v*)&sagg[row * LSTR + c4 * 4];
      *(f4v*)&agg[(size_t)g * 64 + c4 * 4] = vv;
    }
  }
}

// ---------------------------------------------------------------------------
// Node MLP: z = prelu(prelu(cat(x,agg) @ W3 + b3) @ W4 + b4, a_blk)
// ---------------------------------------------------------------------------
__global__ __launch_bounds__(256) void node_mlp_kernel(
    const float* __restrict__ x,
    const float* __restrict__ agg,
    const float* __restrict__ W3, const float* __restrict__ b3,
    const float* __restrict__ a3p,
    const float* __restrict__ W4, const float* __restrict__ b4,
    const float* __restrict__ ablkp,
    float* __restrict__ zout,
    float* __restrict__ part)
{
  const int lane = threadIdx.x & 63;
  const int wv   = threadIdx.x >> 6;
  const int q    = lane >> 4;
  const int r    = lane & 15;
  const int nw   = gridDim.x * 4;
  const int wid  = blockIdx.x * 4 + wv;

  s8v B3f[4][4];
  s8v B4f[2][4];
#pragma unroll
  for (int kk = 0; kk < 4; ++kk)
#pragma unroll
    for (int nt = 0; nt < 4; ++nt) {
      s8v f;
#pragma unroll
      for (int j = 0; j < 8; ++j)
        f[j] = (short)f2bf(W3[(kk * 32 + q * 8 + j) * 64 + nt * 16 + r]);
      B3f[kk][nt] = f;
    }
#pragma unroll
  for (int kk = 0; kk < 2; ++kk)
#pragma unroll
    for (int nt = 0; nt < 4; ++nt) {
      s8v f;
#pragma unroll
      for (int j = 0; j < 8; ++j)
        f[j] = (short)f2bf(W4[(kk * 32 + q * 8 + j) * 64 + nt * 16 + r]);
      B4f[kk][nt] = f;
    }

  float bias3[4], bias4[4];
#pragma unroll
  for (int nt = 0; nt < 4; ++nt) { bias3[nt] = b3[nt * 16 + r]; bias4[nt] = b4[nt * 16 + r]; }
  const float al3 = a3p[0];
  const float alb = ablkp[0];

  __shared__ __align__(16) unsigned short hbuf[4][16 * 72];
  unsigned short* hb = hbuf[wv];

  float bs[4] = {0.f, 0.f, 0.f, 0.f};
  float bq[4] = {0.f, 0.f, 0.f, 0.f};

  for (int t = wid; t < NN / 16; t += nw) {
    const int n = t * 16 + r;
    const f4v* xp = (const f4v*)(x + (size_t)n * 64);
    f4v x0 = xp[q * 2],     x1 = xp[q * 2 + 1];
    f4v x2 = xp[8 + q * 2], x3 = xp[8 + q * 2 + 1];
    const f4v* an4 = (const f4v*)(agg + (size_t)n * 64);
    f4v g0 = an4[q * 2],     g1 = an4[q * 2 + 1];
    f4v g2 = an4[8 + q * 2], g3 = an4[8 + q * 2 + 1];
    s8v a0, a1v, a2v, a3v;
#pragma unroll
    for (int j = 0; j < 4; ++j) {
      a0[j]      = (short)f2bf(x0[j]);
      a0[4 + j]  = (short)f2bf(x1[j]);
      a1v[j]     = (short)f2bf(x2[j]);
      a1v[4 + j] = (short)f2bf(x3[j]);
      a2v[j]     = (short)f2bf(g0[j]);
      a2v[4 + j] = (short)f2bf(g1[j]);
      a3v[j]     = (short)f2bf(g2[j]);
      a3v[4 + j] = (short)f2bf(g3[j]);
    }

    f4v acc[4];
#pragma unroll
    for (int nt = 0; nt < 4; ++nt) {
      f4v c = {0.f, 0.f, 0.f, 0.f};
      c = MFMA16(a0,  B3f[0][nt], c);
      c = MFMA16(a1v, B3f[1][nt], c);
      c = MFMA16(a2v, B3f[2][nt], c);
      c = MFMA16(a3v, B3f[3][nt], c);
      acc[nt] = c;
    }

#pragma unroll
    for (int nt = 0; nt < 4; ++nt)
#pragma unroll
      for (int rg = 0; rg < 4; ++rg) {
        float v = acc[nt][rg] + bias3[nt];
        v = v >= 0.f ? v : al3 * v;
        hb[(q * 4 + rg) * 72 + nt * 16 + r] = f2bf(v);
      }
    s8v p0 = *(const s8v*)(hb + r * 72 + q * 8);
    s8v p1 = *(const s8v*)(hb + r * 72 + 32 + q * 8);

    f4v acc2[4];
#pragma unroll
    for (int nt = 0; nt < 4; ++nt) {
      f4v c = {0.f, 0.f, 0.f, 0.f};
      c = MFMA16(p0, B4f[0][nt], c);
      c = MFMA16(p1, B4f[1][nt], c);
      acc2[nt] = c;
    }

#pragma unroll
    for (int nt = 0; nt < 4; ++nt)
#pragma unroll
      for (int rg = 0; rg < 4; ++rg) {
        float v = acc2[nt][rg] + bias4[nt];
        v = v >= 0.f ? v : alb * v;
        const int row = t * 16 + q * 4 + rg;
        zout[(size_t)row * 64 + nt * 16 + r] = v;
        bs[nt] += v;
        bq[nt] += v * v;
      }
  }

#pragma unroll
  for (int nt = 0; nt < 4; ++nt) {
    float s = bs[nt];
    s += __shfl_xor(s, 16, 64);
    s += __shfl_xor(s, 32, 64);
    float ss = bq[nt];
    ss += __shfl_xor(ss, 16, 64);
    ss += __shfl_xor(ss, 32, 64);
    if (q == 0) {
      atomicAdd(&part[nt * 16 + r], s);
      atomicAdd(&part[64 + nt * 16 + r], ss);
    }
  }
}

// ---------------------------------------------------------------------------
// BatchNorm finalize (in-place on d_out)
// ---------------------------------------------------------------------------
__global__ __launch_bounds__(256) void bn_kernel(
    float* __restrict__ out,
    const float* __restrict__ part,
    const float* __restrict__ gamma,
    const float* __restrict__ beta)
{
  const size_t i = (size_t)blockIdx.x * blockDim.x + threadIdx.x;
  if (i * 4 >= (size_t)NN * 64) return;
  float4 v = ((const float4*)out)[i];
  float e[4] = {v.x, v.y, v.z, v.w};
  const int f0 = (int)((i * 4) & 63);
  const float inv_n = 1.0f / (float)NN;
#pragma unroll
  for (int j = 0; j < 4; ++j) {
    const int f = f0 + j;
    const float mean = part[f] * inv_n;
    const float var  = part[64 + f] * inv_n - mean * mean;
    const float sc = rsqrtf(var + BN_EPS) * gamma[f];
    const float sh = beta[f] - mean * sc;
    e[j] = e[j] * sc + sh;
  }
  ((float4*)out)[i] = make_float4(e[0], e[1], e[2], e[3]);
}

extern "C" void kernel_launch(void* const* d_in, const int* in_sizes, int n_in,
                              void* d_out, int out_size, void* d_ws, size_t ws_size,
                              hipStream_t stream) {
  const float* x  = (const float*)d_in[0];
  const int* ei   = (const int*)d_in[1];
  const float* W1 = (const float*)d_in[2];
  const float* b1 = (const float*)d_in[3];
  const float* a1 = (const float*)d_in[4];
  const float* W2 = (const float*)d_in[5];
  const float* b2 = (const float*)d_in[6];
  const float* a2 = (const float*)d_in[7];
  const float* W3 = (const float*)d_in[8];
  const float* b3 = (const float*)d_in[9];
  const float* a3 = (const float*)d_in[10];
  const float* W4 = (const float*)d_in[11];
  const float* b4 = (const float*)d_in[12];
  const float* ab = (const float*)d_in[13];
  const float* gm = (const float*)d_in[14];
  const float* bt = (const float*)d_in[15];

  float* agg          = (float*)d_ws;                  // [NN*64] f32 (fully written by edge_agg)
  float* part         = agg + (size_t)NN * 64;         // [128] f32 (zeroed)
  unsigned short* F   = (unsigned short*)(part + 128); // [NN*64] bf16
  unsigned short* G   = F + (size_t)NN * 64;           // [NN*64] bf16
  int* hmat           = (int*)(G + (size_t)NN * 64);   // [NBLK*NBKT]
  int* total          = hmat + NBLK * NBKT;            // [NBKT]
  int* boffs          = total + NBKT;                  // [NBKT+1] (+pad)
  int* ebuf           = boffs + NBKT + 8;              // [NE]
  float* out          = (float*)d_out;

  const int* srcp = ei;        // edge_index[0] = src (x_j)
  const int* dstp = ei + NE;   // edge_index[1] = dst (x_i)

  hipMemsetAsync(part, 0, 128 * sizeof(float), stream);
  pre_gemm_kernel<<<dim3(1563), dim3(256), 0, stream>>>(x, W1, F, G);
  hist_kernel<<<dim3(NBLK), dim3(256), 0, stream>>>(dstp, hmat);
  scan_col_kernel<<<dim3(4), dim3(256), 0, stream>>>(hmat, total);
  scan_total_kernel<<<dim3(1), dim3(256), 0, stream>>>(total, boffs);
  scatter_kernel<<<dim3(NBLK), dim3(256), 0, stream>>>(srcp, dstp, hmat, boffs, ebuf);
  edge_agg_kernel<<<dim3(NBKT), dim3(256), 0, stream>>>(F, G, ebuf, boffs, b1, a1, W2, b2, a2, agg);
  node_mlp_kernel<<<dim3(1563), dim3(256), 0, stream>>>(x, agg, W3, b3, a3, W4, b4, ab, out, part);
  bn_kernel<<<dim3(6250), dim3(256), 0, stream>>>(out, part, gm, bt);
}

// Round 6
// 451.893 us; speedup vs baseline: 1.9506x; 1.9506x over previous
//
#include <hip/hip_runtime.h>

#define NN 100000
#define NE 1600000
#define BN_EPS 1e-5f
#define NBKT 1042         // buckets of 96 nodes: 1042*96 = 100032 >= NN
#define BNODE 96          // multiple of 16 -> 6 node-groups per bucket
#define NGRP (NBKT * 6)   // 6252 groups of 16 nodes
#define NBLK 400          // binning blocks
#define CHUNK 4000        // edges per binning block (400*4000 = NE)
#define H2STR 40          // LDS h2^T row stride in shorts (80 B, 16B-aligned rows)

typedef short s8v __attribute__((ext_vector_type(8)));
typedef float f4v __attribute__((ext_vector_type(4)));

__device__ __forceinline__ float bf2f(unsigned short u) {
  union { unsigned u; float f; } v; v.u = ((unsigned)u) << 16; return v.f;
}
__device__ __forceinline__ unsigned short f2bf(float f) {
  union { float f; unsigned u; } v; v.f = f;
  return (unsigned short)((v.u + 0x7FFFu + ((v.u >> 16) & 1u)) >> 16);
}

#define MFMA16(a, b, c) __builtin_amdgcn_mfma_f32_16x16x32_bf16((a), (b), (c), 0, 0, 0)

// ---------------------------------------------------------------------------
// Pre-GEMM: F = X @ W1[0:64,:], G = X @ W1[64:128,:]  (bf16 [NN][64])
// ---------------------------------------------------------------------------
__global__ __launch_bounds__(256) void pre_gemm_kernel(
    const float* __restrict__ x, const float* __restrict__ W1,
    unsigned short* __restrict__ F, unsigned short* __restrict__ G)
{
  const int lane = threadIdx.x & 63;
  const int wv   = threadIdx.x >> 6;
  const int q    = lane >> 4;
  const int r    = lane & 15;
  const int nw   = gridDim.x * 4;
  const int wid  = blockIdx.x * 4 + wv;

  s8v Bt[2][4], Bb[2][4];
#pragma unroll
  for (int kk = 0; kk < 2; ++kk)
#pragma unroll
    for (int nt = 0; nt < 4; ++nt) {
      s8v ft, fb;
#pragma unroll
      for (int j = 0; j < 8; ++j) {
        ft[j] = (short)f2bf(W1[(kk * 32 + q * 8 + j) * 64 + nt * 16 + r]);
        fb[j] = (short)f2bf(W1[(64 + kk * 32 + q * 8 + j) * 64 + nt * 16 + r]);
      }
      Bt[kk][nt] = ft; Bb[kk][nt] = fb;
    }

  for (int t = wid; t < NN / 16; t += nw) {
    const int n = t * 16 + r;
    const f4v* xp = (const f4v*)(x + (size_t)n * 64);
    f4v x0 = xp[q * 2],     x1 = xp[q * 2 + 1];
    f4v x2 = xp[8 + q * 2], x3 = xp[8 + q * 2 + 1];
    s8v a0, a1v;
#pragma unroll
    for (int j = 0; j < 4; ++j) {
      a0[j]      = (short)f2bf(x0[j]);
      a0[4 + j]  = (short)f2bf(x1[j]);
      a1v[j]     = (short)f2bf(x2[j]);
      a1v[4 + j] = (short)f2bf(x3[j]);
    }
    f4v aF[4], aG[4];
#pragma unroll
    for (int nt = 0; nt < 4; ++nt) {
      f4v c = {0.f, 0.f, 0.f, 0.f};
      c = MFMA16(a0,  Bt[0][nt], c);
      c = MFMA16(a1v, Bt[1][nt], c);
      aF[nt] = c;
      f4v d = {0.f, 0.f, 0.f, 0.f};
      d = MFMA16(a0,  Bb[0][nt], d);
      d = MFMA16(a1v, Bb[1][nt], d);
      aG[nt] = d;
    }
#pragma unroll
    for (int nt = 0; nt < 4; ++nt)
#pragma unroll
      for (int rg = 0; rg < 4; ++rg) {
        const size_t idx = (size_t)(t * 16 + q * 4 + rg) * 64 + nt * 16 + r;
        F[idx] = f2bf(aF[nt][rg]);
        G[idx] = f2bf(aG[nt][rg]);
      }
  }
}

// ---------------------------------------------------------------------------
// Binning pass 1: per-block LDS histogram -> hmat TRANSPOSED [bucket][block]
// ---------------------------------------------------------------------------
__global__ __launch_bounds__(256) void hist_kernel(
    const int* __restrict__ dstp, int* __restrict__ hmat)
{
  __shared__ int lh[NBKT];
  const int t = threadIdx.x;
  for (int i = t; i < NBKT; i += 256) lh[i] = 0;
  __syncthreads();
  const int base = blockIdx.x * CHUNK;
#pragma unroll
  for (int i = 0; i < 16; ++i) {
    const int o = i * 256 + t;
    if (o < CHUNK) atomicAdd(&lh[dstp[base + o] / BNODE], 1);
  }
  __syncthreads();
  for (int i = t; i < NBKT; i += 256)
    hmat[i * NBLK + blockIdx.x] = lh[i];
}

// ---------------------------------------------------------------------------
// Binning pass 2a: per-bucket exclusive scan over blocks (contiguous int4)
// ---------------------------------------------------------------------------
__global__ __launch_bounds__(256) void scan_col_kernel(
    int* __restrict__ hmat, int* __restrict__ total)
{
  const int b = blockIdx.x * 256 + threadIdx.x;
  if (b >= NBKT) return;
  int4* hp = (int4*)(hmat + (size_t)b * NBLK);
  int run = 0;
#pragma unroll 4
  for (int i = 0; i < NBLK / 4; ++i) {
    int4 v = hp[i]; int4 o;
    o.x = run; run += v.x;
    o.y = run; run += v.y;
    o.z = run; run += v.z;
    o.w = run; run += v.w;
    hp[i] = o;
  }
  total[b] = run;
}

// ---------------------------------------------------------------------------
// Binning pass 2b: exclusive scan of total[NBKT] -> boffs[NBKT+1]
// ---------------------------------------------------------------------------
__global__ void scan_total_kernel(const int* __restrict__ total, int* __restrict__ boffs)
{
  const int tid = threadIdx.x;                    // 1 block x 256
  const int lane = tid & 63, wv = tid >> 6;
  __shared__ int wsum[4], wbase[4];
  int v[5]; int s = 0;
#pragma unroll
  for (int j = 0; j < 5; ++j) {
    const int idx = tid * 5 + j;
    v[j] = (idx < NBKT) ? total[idx] : 0;
    s += v[j];
  }
  int inc = s;
#pragma unroll
  for (int d = 1; d < 64; d <<= 1) { int t = __shfl_up(inc, d, 64); if (lane >= d) inc += t; }
  if (lane == 63) wsum[wv] = inc;
  __syncthreads();
  if (tid == 0) { int run = 0; for (int k = 0; k < 4; ++k) { wbase[k] = run; run += wsum[k]; } }
  __syncthreads();
  int run = wbase[wv] + inc - s;
#pragma unroll
  for (int j = 0; j < 5; ++j) {
    const int idx = tid * 5 + j;
    if (idx < NBKT) boffs[idx] = run;
    run += v[j];
  }
  if (tid == 0) boffs[NBKT] = NE;
}

// ---------------------------------------------------------------------------
// Binning pass 3: scatter edges into bucket-ordered ebuf; LDS cursors only.
// word = (src << 7) | (dst - bucket*96)
// ---------------------------------------------------------------------------
__global__ __launch_bounds__(256) void scatter_kernel(
    const int* __restrict__ srcp, const int* __restrict__ dstp,
    const int* __restrict__ hmat, const int* __restrict__ boffs,
    int* __restrict__ ebuf)
{
  __shared__ int lcur[NBKT];
  const int t = threadIdx.x;
  for (int i = t; i < NBKT; i += 256)
    lcur[i] = boffs[i] + hmat[i * NBLK + blockIdx.x];
  __syncthreads();
  const int base = blockIdx.x * CHUNK;
#pragma unroll
  for (int i = 0; i < 16; ++i) {
    const int o = i * 256 + t;
    if (o < CHUNK) {
      const int d = dstp[base + o];
      const int s = srcp[base + o];
      const int b = d / BNODE;
      const int p = atomicAdd(&lcur[b], 1);
      ebuf[p] = (s << 7) | (d - b * BNODE);
    }
  }
}

// ---------------------------------------------------------------------------
// Sort stage 2: within each 96-node bucket, counting-sort to full node order.
// Also emits the 16-node group offsets gofs[NGRP+1].
// ---------------------------------------------------------------------------
__global__ __launch_bounds__(256) void sort2_kernel(
    const int* __restrict__ ebuf, const int* __restrict__ boffs,
    int* __restrict__ ebuf2, int* __restrict__ gofs)
{
  __shared__ int cnt[BNODE], cur[BNODE];
  const int bkt = blockIdx.x;
  const int start = boffs[bkt], end = boffs[bkt + 1];
  const int n = end - start;
  const int tid = threadIdx.x;
  if (tid < BNODE) cnt[tid] = 0;
  __syncthreads();
  for (int i = tid; i < n; i += 256) atomicAdd(&cnt[ebuf[start + i] & 127], 1);
  __syncthreads();
  if (tid == 0) {
    int run = 0;
    for (int j = 0; j < BNODE; ++j) {
      if ((j & 15) == 0) gofs[bkt * 6 + (j >> 4)] = start + run;
      cur[j] = run;
      run += cnt[j];
    }
    if (bkt == NBKT - 1) gofs[NGRP] = NE;
  }
  __syncthreads();
  for (int i = tid; i < n; i += 256) {
    const int w = ebuf[start + i];
    const int p = atomicAdd(&cur[w & 127], 1);
    ebuf2[start + p] = w;
  }
}

// ---------------------------------------------------------------------------
// Edge MLP + aggregation, RMW-free: each wave owns one 16-node group.
// Per 32-edge chunk: h1 = prelu(F[dst]+G[src]+b1) (A/B-frag layout),
// h2^T = prelu(W2^T @ h1^T + b2) via MFMA (lane=edge, reg=feature),
// LDS transpose to (lane=feature, reg=edge), then
// AGG(16n x 64f) += S^T(16x32) @ H2(32x64) via MFMA with 0/1 indicator S.
// Accumulator lives in AGPRs; ONE plain store per node. Zero atomics.
// ---------------------------------------------------------------------------
__global__ __launch_bounds__(256) void edge_agg_kernel(
    const unsigned short* __restrict__ F, const unsigned short* __restrict__ G,
    const int* __restrict__ ebuf2, const int* __restrict__ gofs,
    const float* __restrict__ b1, const float* __restrict__ a1p,
    const float* __restrict__ W2, const float* __restrict__ b2,
    const float* __restrict__ a2p,
    float* __restrict__ agg)
{
  const int lane = threadIdx.x & 63;
  const int wv   = threadIdx.x >> 6;
  const int q    = lane >> 4;
  const int r    = lane & 15;

  __shared__ __align__(16) unsigned short h2t[4][64 * H2STR]; // per-wave h2^T
  __shared__ __align__(16) unsigned short dbf[4][32];          // per-wave dloc16
  unsigned short* hb = h2t[wv];
  unsigned short* db = dbf[wv];

  const int g = blockIdx.x * 4 + wv;
  if (g >= NGRP) return;                      // no barriers below: safe

  // W2^T A-fragments: A[m=out=ot*16+r][k=in=kk*32+q*8+j]
  s8v W2T[2][4];
#pragma unroll
  for (int kk = 0; kk < 2; ++kk)
#pragma unroll
    for (int ot = 0; ot < 4; ++ot) {
      s8v f;
#pragma unroll
      for (int j = 0; j < 8; ++j)
        f[j] = (short)f2bf(W2[(kk * 32 + q * 8 + j) * 64 + ot * 16 + r]);
      W2T[kk][ot] = f;
    }

  float b1f[16];
#pragma unroll
  for (int j = 0; j < 8; ++j) {
    b1f[j]     = b1[q * 8 + j];
    b1f[8 + j] = b1[32 + q * 8 + j];
  }
  float b2v[4][4];                            // [ot][rg] = b2[ot*16+q*4+rg]
#pragma unroll
  for (int ot = 0; ot < 4; ++ot)
#pragma unroll
    for (int rg = 0; rg < 4; ++rg) b2v[ot][rg] = b2[ot * 16 + q * 4 + rg];
  const float al1 = a1p[0];
  const float al2 = a2p[0];

  const int start  = gofs[g], end = gofs[g + 1];
  const int g0     = g * 16;                  // first global node of group
  const int nbase  = (g / 6) * BNODE;         // bucket's first global node
  const int base16 = (g % 6) * 16;            // group's base dloc in bucket

  f4v acc[4];
#pragma unroll
  for (int ft = 0; ft < 4; ++ft) acc[ft] = (f4v){0.f, 0.f, 0.f, 0.f};

  for (int c0 = start; c0 < end; c0 += 32) {
#pragma unroll
    for (int tu = 0; tu < 2; ++tu) {
      const int e  = c0 + tu * 16 + r;
      const int ec = e < end ? e : end - 1;
      const int w  = ebuf2[ec];
      const int dl = w & 127;
      const int sn = w >> 7;
      const int dn = nbase + dl;
      if (q == 0) db[tu * 16 + r] = (e < end) ? (unsigned short)(dl - base16)
                                              : (unsigned short)0xFF;

      s8v fa = *(const s8v*)(F + (size_t)dn * 64 + q * 8);
      s8v fb = *(const s8v*)(F + (size_t)dn * 64 + 32 + q * 8);
      s8v ga = *(const s8v*)(G + (size_t)sn * 64 + q * 8);
      s8v gb = *(const s8v*)(G + (size_t)sn * 64 + 32 + q * 8);

      s8v p0, p1;
#pragma unroll
      for (int j = 0; j < 8; ++j) {
        float v = bf2f((unsigned short)fa[j]) + bf2f((unsigned short)ga[j]) + b1f[j];
        v = v >= 0.f ? v : al1 * v;
        p0[j] = (short)f2bf(v);
        float u = bf2f((unsigned short)fb[j]) + bf2f((unsigned short)gb[j]) + b1f[8 + j];
        u = u >= 0.f ? u : al1 * u;
        p1[j] = (short)f2bf(u);
      }

      // h2^T = prelu(W2^T @ h1^T + b2): C col=lane=edge, row=q*4+rg=feature
#pragma unroll
      for (int ot = 0; ot < 4; ++ot) {
        f4v c = {0.f, 0.f, 0.f, 0.f};
        c = MFMA16(W2T[0][ot], p0, c);
        c = MFMA16(W2T[1][ot], p1, c);
#pragma unroll
        for (int rg = 0; rg < 4; ++rg) {
          float v = c[rg] + b2v[ot][rg];
          v = v >= 0.f ? v : al2 * v;
          hb[(ot * 16 + q * 4 + rg) * H2STR + tu * 16 + r] = f2bf(v);
        }
      }
    }

    // S^T indicator A-frag: A[m=node=r][k=edge=q*8+j]
    s8v dv = *(const s8v*)(db + q * 8);
    s8v sA;
#pragma unroll
    for (int j = 0; j < 8; ++j)
      sA[j] = (short)(((int)(unsigned short)dv[j] == r) ? 0x3F80 : 0);

    // AGG += S^T @ H2 : B[k=edge=q*8+j][n=feat=ft*16+r]
#pragma unroll
    for (int ft = 0; ft < 4; ++ft) {
      s8v bf = *(const s8v*)(hb + (ft * 16 + r) * H2STR + q * 8);
      acc[ft] = MFMA16(sA, bf, acc[ft]);
    }
  }

  // flush: one plain store per (node, feature)
#pragma unroll
  for (int ft = 0; ft < 4; ++ft)
#pragma unroll
    for (int rg = 0; rg < 4; ++rg) {
      const int node = g0 + q * 4 + rg;
      if (node < NN) agg[(size_t)node * 64 + ft * 16 + r] = acc[ft][rg];
    }
}

// ---------------------------------------------------------------------------
// Node MLP: z = prelu(prelu(cat(x,agg) @ W3 + b3) @ W4 + b4, a_blk)
// ---------------------------------------------------------------------------
__global__ __launch_bounds__(256) void node_mlp_kernel(
    const float* __restrict__ x,
    const float* __restrict__ agg,
    const float* __restrict__ W3, const float* __restrict__ b3,
    const float* __restrict__ a3p,
    const float* __restrict__ W4, const float* __restrict__ b4,
    const float* __restrict__ ablkp,
    float* __restrict__ zout,
    float* __restrict__ part)
{
  const int lane = threadIdx.x & 63;
  const int wv   = threadIdx.x >> 6;
  const int q    = lane >> 4;
  const int r    = lane & 15;
  const int nw   = gridDim.x * 4;
  const int wid  = blockIdx.x * 4 + wv;

  s8v B3f[4][4];
  s8v B4f[2][4];
#pragma unroll
  for (int kk = 0; kk < 4; ++kk)
#pragma unroll
    for (int nt = 0; nt < 4; ++nt) {
      s8v f;
#pragma unroll
      for (int j = 0; j < 8; ++j)
        f[j] = (short)f2bf(W3[(kk * 32 + q * 8 + j) * 64 + nt * 16 + r]);
      B3f[kk][nt] = f;
    }
#pragma unroll
  for (int kk = 0; kk < 2; ++kk)
#pragma unroll
    for (int nt = 0; nt < 4; ++nt) {
      s8v f;
#pragma unroll
      for (int j = 0; j < 8; ++j)
        f[j] = (short)f2bf(W4[(kk * 32 + q * 8 + j) * 64 + nt * 16 + r]);
      B4f[kk][nt] = f;
    }

  float bias3[4], bias4[4];
#pragma unroll
  for (int nt = 0; nt < 4; ++nt) { bias3[nt] = b3[nt * 16 + r]; bias4[nt] = b4[nt * 16 + r]; }
  const float al3 = a3p[0];
  const float alb = ablkp[0];

  __shared__ __align__(16) unsigned short hbuf[4][16 * 72];
  unsigned short* hb = hbuf[wv];

  float bs[4] = {0.f, 0.f, 0.f, 0.f};
  float bq[4] = {0.f, 0.f, 0.f, 0.f};

  for (int t = wid; t < NN / 16; t += nw) {
    const int n = t * 16 + r;
    const f4v* xp = (const f4v*)(x + (size_t)n * 64);
    f4v x0 = xp[q * 2],     x1 = xp[q * 2 + 1];
    f4v x2 = xp[8 + q * 2], x3 = xp[8 + q * 2 + 1];
    const f4v* an4 = (const f4v*)(agg + (size_t)n * 64);
    f4v g0 = an4[q * 2],     g1 = an4[q * 2 + 1];
    f4v g2 = an4[8 + q * 2], g3 = an4[8 + q * 2 + 1];
    s8v a0, a1v, a2v, a3v;
#pragma unroll
    for (int j = 0; j < 4; ++j) {
      a0[j]      = (short)f2bf(x0[j]);
      a0[4 + j]  = (short)f2bf(x1[j]);
      a1v[j]     = (short)f2bf(x2[j]);
      a1v[4 + j] = (short)f2bf(x3[j]);
      a2v[j]     = (short)f2bf(g0[j]);
      a2v[4 + j] = (short)f2bf(g1[j]);
      a3v[j]     = (short)f2bf(g2[j]);
      a3v[4 + j] = (short)f2bf(g3[j]);
    }

    f4v acc[4];
#pragma unroll
    for (int nt = 0; nt < 4; ++nt) {
      f4v c = {0.f, 0.f, 0.f, 0.f};
      c = MFMA16(a0,  B3f[0][nt], c);
      c = MFMA16(a1v, B3f[1][nt], c);
      c = MFMA16(a2v, B3f[2][nt], c);
      c = MFMA16(a3v, B3f[3][nt], c);
      acc[nt] = c;
    }

#pragma unroll
    for (int nt = 0; nt < 4; ++nt)
#pragma unroll
      for (int rg = 0; rg < 4; ++rg) {
        float v = acc[nt][rg] + bias3[nt];
        v = v >= 0.f ? v : al3 * v;
        hb[(q * 4 + rg) * 72 + nt * 16 + r] = f2bf(v);
      }
    s8v p0 = *(const s8v*)(hb + r * 72 + q * 8);
    s8v p1 = *(const s8v*)(hb + r * 72 + 32 + q * 8);

    f4v acc2[4];
#pragma unroll
    for (int nt = 0; nt < 4; ++nt) {
      f4v c = {0.f, 0.f, 0.f, 0.f};
      c = MFMA16(p0, B4f[0][nt], c);
      c = MFMA16(p1, B4f[1][nt], c);
      acc2[nt] = c;
    }

#pragma unroll
    for (int nt = 0; nt < 4; ++nt)
#pragma unroll
      for (int rg = 0; rg < 4; ++rg) {
        float v = acc2[nt][rg] + bias4[nt];
        v = v >= 0.f ? v : alb * v;
        const int row = t * 16 + q * 4 + rg;
        zout[(size_t)row * 64 + nt * 16 + r] = v;
        bs[nt] += v;
        bq[nt] += v * v;
      }
  }

#pragma unroll
  for (int nt = 0; nt < 4; ++nt) {
    float s = bs[nt];
    s += __shfl_xor(s, 16, 64);
    s += __shfl_xor(s, 32, 64);
    float ss = bq[nt];
    ss += __shfl_xor(ss, 16, 64);
    ss += __shfl_xor(ss, 32, 64);
    if (q == 0) {
      atomicAdd(&part[nt * 16 + r], s);
      atomicAdd(&part[64 + nt * 16 + r], ss);
    }
  }
}

// ---------------------------------------------------------------------------
// BatchNorm finalize (in-place on d_out)
// ---------------------------------------------------------------------------
__global__ __launch_bounds__(256) void bn_kernel(
    float* __restrict__ out,
    const float* __restrict__ part,
    const float* __restrict__ gamma,
    const float* __restrict__ beta)
{
  const size_t i = (size_t)blockIdx.x * blockDim.x + threadIdx.x;
  if (i * 4 >= (size_t)NN * 64) return;
  float4 v = ((const float4*)out)[i];
  float e[4] = {v.x, v.y, v.z, v.w};
  const int f0 = (int)((i * 4) & 63);
  const float inv_n = 1.0f / (float)NN;
#pragma unroll
  for (int j = 0; j < 4; ++j) {
    const int f = f0 + j;
    const float mean = part[f] * inv_n;
    const float var  = part[64 + f] * inv_n - mean * mean;
    const float sc = rsqrtf(var + BN_EPS) * gamma[f];
    const float sh = beta[f] - mean * sc;
    e[j] = e[j] * sc + sh;
  }
  ((float4*)out)[i] = make_float4(e[0], e[1], e[2], e[3]);
}

extern "C" void kernel_launch(void* const* d_in, const int* in_sizes, int n_in,
                              void* d_out, int out_size, void* d_ws, size_t ws_size,
                              hipStream_t stream) {
  const float* x  = (const float*)d_in[0];
  const int* ei   = (const int*)d_in[1];
  const float* W1 = (const float*)d_in[2];
  const float* b1 = (const float*)d_in[3];
  const float* a1 = (const float*)d_in[4];
  const float* W2 = (const float*)d_in[5];
  const float* b2 = (const float*)d_in[6];
  const float* a2 = (const float*)d_in[7];
  const float* W3 = (const float*)d_in[8];
  const float* b3 = (const float*)d_in[9];
  const float* a3 = (const float*)d_in[10];
  const float* W4 = (const float*)d_in[11];
  const float* b4 = (const float*)d_in[12];
  const float* ab = (const float*)d_in[13];
  const float* gm = (const float*)d_in[14];
  const float* bt = (const float*)d_in[15];

  float* agg          = (float*)d_ws;                  // [NN*64] f32 (fully written)
  float* part         = agg + (size_t)NN * 64;         // [128] f32 (zeroed)
  unsigned short* F   = (unsigned short*)(part + 128); // [NN*64] bf16
  unsigned short* G   = F + (size_t)NN * 64;           // [NN*64] bf16
  int* hmat           = (int*)(G + (size_t)NN * 64);   // [NBKT*NBLK]
  int* total          = hmat + (size_t)NBKT * NBLK;    // [NBKT]
  int* boffs          = total + NBKT;                  // [NBKT+1] (+pad)
  int* gofs           = boffs + NBKT + 8;              // [NGRP+1] (+pad)
  int* ebuf           = gofs + NGRP + 8;               // [NE]
  int* ebuf2          = ebuf + NE;                     // [NE]
  float* out          = (float*)d_out;

  const int* srcp = ei;        // edge_index[0] = src (x_j)
  const int* dstp = ei + NE;   // edge_index[1] = dst (x_i)

  hipMemsetAsync(part, 0, 128 * sizeof(float), stream);
  pre_gemm_kernel<<<dim3(1563), dim3(256), 0, stream>>>(x, W1, F, G);
  hist_kernel<<<dim3(NBLK), dim3(256), 0, stream>>>(dstp, hmat);
  scan_col_kernel<<<dim3((NBKT + 255) / 256), dim3(256), 0, stream>>>(hmat, total);
  scan_total_kernel<<<dim3(1), dim3(256), 0, stream>>>(total, boffs);
  scatter_kernel<<<dim3(NBLK), dim3(256), 0, stream>>>(srcp, dstp, hmat, boffs, ebuf);
  sort2_kernel<<<dim3(NBKT), dim3(256), 0, stream>>>(ebuf, boffs, ebuf2, gofs);
  edge_agg_kernel<<<dim3((NGRP + 3) / 4), dim3(256), 0, stream>>>(
      F, G, ebuf2, gofs, b1, a1, W2, b2, a2, agg);
  node_mlp_kernel<<<dim3(1563), dim3(256), 0, stream>>>(
      x, agg, W3, b3, a3, W4, b4, ab, out, part);
  bn_kernel<<<dim3(6250), dim3(256), 0, stream>>>(out, part, gm, bt);
}

// Round 7
// 348.670 us; speedup vs baseline: 2.5281x; 1.2960x over previous
//
#include <hip/hip_runtime.h>

#define NN 100000
#define NE 1600000
#define BN_EPS 1e-5f
#define NBKT 1042         // buckets of 96 nodes: 1042*96 = 100032 >= NN
#define BNODE 96          // multiple of 16 -> 6 node-groups per bucket
#define NGRP (NBKT * 6)   // 6252 groups of 16 nodes
#define NBLK 400          // binning blocks
#define CHUNK 4000        // edges per binning block (400*4000 = NE)
#define H2STR 40          // LDS h2^T row stride in shorts (80 B, 16B-aligned rows)
#define NFRAG 48          // packed weight fragments

typedef short s8v __attribute__((ext_vector_type(8)));
typedef float f4v __attribute__((ext_vector_type(4)));

__device__ __forceinline__ float bf2f(unsigned short u) {
  union { unsigned u; float f; } v; v.u = ((unsigned)u) << 16; return v.f;
}
__device__ __forceinline__ unsigned short f2bf(float f) {
  union { float f; unsigned u; } v; v.f = f;
  return (unsigned short)((v.u + 0x7FFFu + ((v.u >> 16) & 1u)) >> 16);
}
__device__ __forceinline__ s8v ldfrag(const unsigned short* __restrict__ pack,
                                      int f, int lane) {
  return *(const s8v*)(pack + ((size_t)f * 64 + lane) * 8);
}

#define MFMA16(a, b, c) __builtin_amdgcn_mfma_f32_16x16x32_bf16((a), (b), (c), 0, 0, 0)

// ---------------------------------------------------------------------------
// Weight pack: all MFMA fragments pre-swizzled to [frag][lane][8] bf16 so
// consumers load each fragment as ONE coalesced 16B read.
// frag map: 0..7 W1 top | 8..15 W1 bot | 16..23 W2 | 24..39 W3 | 40..47 W4
// element j of (frag,lane): src[(rowoff + kk*32 + q*8 + j)*64 + nt*16 + r]
// ---------------------------------------------------------------------------
__global__ __launch_bounds__(256) void pack_kernel(
    const float* __restrict__ W1, const float* __restrict__ W2,
    const float* __restrict__ W3, const float* __restrict__ W4,
    unsigned short* __restrict__ pack)
{
  for (int it = threadIdx.x; it < NFRAG * 64; it += 256) {
    const int f = it >> 6;
    const int lane = it & 63;
    const int q = lane >> 4, r = lane & 15;
    const float* src; int rowoff, fi;
    if (f < 8)       { src = W1; rowoff = 0;  fi = f; }
    else if (f < 16) { src = W1; rowoff = 64; fi = f - 8; }
    else if (f < 24) { src = W2; rowoff = 0;  fi = f - 16; }
    else if (f < 40) { src = W3; rowoff = 0;  fi = f - 24; }
    else             { src = W4; rowoff = 0;  fi = f - 40; }
    const int kk = fi >> 2, nt = fi & 3;
    unsigned short tmp[8];
#pragma unroll
    for (int j = 0; j < 8; ++j)
      tmp[j] = f2bf(src[(size_t)(rowoff + kk * 32 + q * 8 + j) * 64 + nt * 16 + r]);
    *(s8v*)(pack + ((size_t)f * 64 + lane) * 8) = *(const s8v*)tmp;
  }
}

// ---------------------------------------------------------------------------
// Pre-GEMM: F = X @ W1[0:64,:], G = X @ W1[64:128,:]  (bf16 [NN][64])
// ---------------------------------------------------------------------------
__global__ __launch_bounds__(256) void pre_gemm_kernel(
    const float* __restrict__ x, const unsigned short* __restrict__ pack,
    unsigned short* __restrict__ F, unsigned short* __restrict__ G)
{
  const int lane = threadIdx.x & 63;
  const int wv   = threadIdx.x >> 6;
  const int q    = lane >> 4;
  const int r    = lane & 15;
  const int nw   = gridDim.x * 4;
  const int wid  = blockIdx.x * 4 + wv;

  s8v Bt[2][4], Bb[2][4];
#pragma unroll
  for (int kk = 0; kk < 2; ++kk)
#pragma unroll
    for (int nt = 0; nt < 4; ++nt) {
      Bt[kk][nt] = ldfrag(pack, kk * 4 + nt, lane);
      Bb[kk][nt] = ldfrag(pack, 8 + kk * 4 + nt, lane);
    }

  for (int t = wid; t < NN / 16; t += nw) {
    const int n = t * 16 + r;
    const f4v* xp = (const f4v*)(x + (size_t)n * 64);
    f4v x0 = xp[q * 2],     x1 = xp[q * 2 + 1];
    f4v x2 = xp[8 + q * 2], x3 = xp[8 + q * 2 + 1];
    s8v a0, a1v;
#pragma unroll
    for (int j = 0; j < 4; ++j) {
      a0[j]      = (short)f2bf(x0[j]);
      a0[4 + j]  = (short)f2bf(x1[j]);
      a1v[j]     = (short)f2bf(x2[j]);
      a1v[4 + j] = (short)f2bf(x3[j]);
    }
    f4v aF[4], aG[4];
#pragma unroll
    for (int nt = 0; nt < 4; ++nt) {
      f4v c = {0.f, 0.f, 0.f, 0.f};
      c = MFMA16(a0,  Bt[0][nt], c);
      c = MFMA16(a1v, Bt[1][nt], c);
      aF[nt] = c;
      f4v d = {0.f, 0.f, 0.f, 0.f};
      d = MFMA16(a0,  Bb[0][nt], d);
      d = MFMA16(a1v, Bb[1][nt], d);
      aG[nt] = d;
    }
#pragma unroll
    for (int nt = 0; nt < 4; ++nt)
#pragma unroll
      for (int rg = 0; rg < 4; ++rg) {
        const size_t idx = (size_t)(t * 16 + q * 4 + rg) * 64 + nt * 16 + r;
        F[idx] = f2bf(aF[nt][rg]);
        G[idx] = f2bf(aG[nt][rg]);
      }
  }
}

// ---------------------------------------------------------------------------
// Binning pass 1: per-block LDS histogram -> hmat TRANSPOSED [bucket][block]
// ---------------------------------------------------------------------------
__global__ __launch_bounds__(256) void hist_kernel(
    const int* __restrict__ dstp, int* __restrict__ hmat)
{
  __shared__ int lh[NBKT];
  const int t = threadIdx.x;
  for (int i = t; i < NBKT; i += 256) lh[i] = 0;
  __syncthreads();
  const int base = blockIdx.x * CHUNK;
#pragma unroll
  for (int i = 0; i < 16; ++i) {
    const int o = i * 256 + t;
    if (o < CHUNK) atomicAdd(&lh[dstp[base + o] / BNODE], 1);
  }
  __syncthreads();
  for (int i = t; i < NBKT; i += 256)
    hmat[i * NBLK + blockIdx.x] = lh[i];
}

// ---------------------------------------------------------------------------
// Binning pass 2a: per-bucket exclusive scan over blocks (contiguous int4)
// ---------------------------------------------------------------------------
__global__ __launch_bounds__(256) void scan_col_kernel(
    int* __restrict__ hmat, int* __restrict__ total)
{
  const int b = blockIdx.x * 256 + threadIdx.x;
  if (b >= NBKT) return;
  int4* hp = (int4*)(hmat + (size_t)b * NBLK);
  int run = 0;
#pragma unroll 4
  for (int i = 0; i < NBLK / 4; ++i) {
    int4 v = hp[i]; int4 o;
    o.x = run; run += v.x;
    o.y = run; run += v.y;
    o.z = run; run += v.z;
    o.w = run; run += v.w;
    hp[i] = o;
  }
  total[b] = run;
}

// ---------------------------------------------------------------------------
// Binning pass 2b: exclusive scan of total[NBKT] -> boffs[NBKT+1]
// ---------------------------------------------------------------------------
__global__ void scan_total_kernel(const int* __restrict__ total, int* __restrict__ boffs)
{
  const int tid = threadIdx.x;                    // 1 block x 256
  const int lane = tid & 63, wv = tid >> 6;
  __shared__ int wsum[4], wbase[4];
  int v[5]; int s = 0;
#pragma unroll
  for (int j = 0; j < 5; ++j) {
    const int idx = tid * 5 + j;
    v[j] = (idx < NBKT) ? total[idx] : 0;
    s += v[j];
  }
  int inc = s;
#pragma unroll
  for (int d = 1; d < 64; d <<= 1) { int t = __shfl_up(inc, d, 64); if (lane >= d) inc += t; }
  if (lane == 63) wsum[wv] = inc;
  __syncthreads();
  if (tid == 0) { int run = 0; for (int k = 0; k < 4; ++k) { wbase[k] = run; run += wsum[k]; } }
  __syncthreads();
  int run = wbase[wv] + inc - s;
#pragma unroll
  for (int j = 0; j < 5; ++j) {
    const int idx = tid * 5 + j;
    if (idx < NBKT) boffs[idx] = run;
    run += v[j];
  }
  if (tid == 0) boffs[NBKT] = NE;
}

// ---------------------------------------------------------------------------
// Binning pass 3: scatter edges into bucket-ordered ebuf; LDS cursors only.
// word = (src << 7) | (dst - bucket*96)
// ---------------------------------------------------------------------------
__global__ __launch_bounds__(256) void scatter_kernel(
    const int* __restrict__ srcp, const int* __restrict__ dstp,
    const int* __restrict__ hmat, const int* __restrict__ boffs,
    int* __restrict__ ebuf)
{
  __shared__ int lcur[NBKT];
  const int t = threadIdx.x;
  for (int i = t; i < NBKT; i += 256)
    lcur[i] = boffs[i] + hmat[i * NBLK + blockIdx.x];
  __syncthreads();
  const int base = blockIdx.x * CHUNK;
#pragma unroll
  for (int i = 0; i < 16; ++i) {
    const int o = i * 256 + t;
    if (o < CHUNK) {
      const int d = dstp[base + o];
      const int s = srcp[base + o];
      const int b = d / BNODE;
      const int p = atomicAdd(&lcur[b], 1);
      ebuf[p] = (s << 7) | (d - b * BNODE);
    }
  }
}

// ---------------------------------------------------------------------------
// Sort stage 2: within each 96-node bucket, counting-sort to full node order.
// Also emits the 16-node group offsets gofs[NGRP+1].
// ---------------------------------------------------------------------------
__global__ __launch_bounds__(256) void sort2_kernel(
    const int* __restrict__ ebuf, const int* __restrict__ boffs,
    int* __restrict__ ebuf2, int* __restrict__ gofs)
{
  __shared__ int cnt[BNODE], cur[BNODE];
  const int bkt = blockIdx.x;
  const int start = boffs[bkt], end = boffs[bkt + 1];
  const int n = end - start;
  const int tid = threadIdx.x;
  if (tid < BNODE) cnt[tid] = 0;
  __syncthreads();
  for (int i = tid; i < n; i += 256) atomicAdd(&cnt[ebuf[start + i] & 127], 1);
  __syncthreads();
  if (tid == 0) {
    int run = 0;
    for (int j = 0; j < BNODE; ++j) {
      if ((j & 15) == 0) gofs[bkt * 6 + (j >> 4)] = start + run;
      cur[j] = run;
      run += cnt[j];
    }
    if (bkt == NBKT - 1) gofs[NGRP] = NE;
  }
  __syncthreads();
  for (int i = tid; i < n; i += 256) {
    const int w = ebuf[start + i];
    const int p = atomicAdd(&cur[w & 127], 1);
    ebuf2[start + p] = w;
  }
}

// ---------------------------------------------------------------------------
// Edge MLP + aggregation, RMW-free: each wave owns one 16-node group.
// h2^T via transposed MFMA; AGG += S^T @ H2 with 0/1 indicator; AGPR acc;
// one plain store per node. Zero atomics.
// ---------------------------------------------------------------------------
__global__ __launch_bounds__(256) void edge_agg_kernel(
    const unsigned short* __restrict__ F, const unsigned short* __restrict__ G,
    const int* __restrict__ ebuf2, const int* __restrict__ gofs,
    const unsigned short* __restrict__ pack,
    const float* __restrict__ b1, const float* __restrict__ a1p,
    const float* __restrict__ b2, const float* __restrict__ a2p,
    float* __restrict__ agg)
{
  const int lane = threadIdx.x & 63;
  const int wv   = threadIdx.x >> 6;
  const int q    = lane >> 4;
  const int r    = lane & 15;

  __shared__ __align__(16) unsigned short h2t[4][64 * H2STR]; // per-wave h2^T
  __shared__ __align__(16) unsigned short dbf[4][32];          // per-wave dloc16
  unsigned short* hb = h2t[wv];
  unsigned short* db = dbf[wv];

  const int g = blockIdx.x * 4 + wv;
  if (g >= NGRP) return;                      // no barriers below: safe

  // W2^T A-fragments == W2 B-fragment pack (same index expression)
  s8v W2T[2][4];
#pragma unroll
  for (int kk = 0; kk < 2; ++kk)
#pragma unroll
    for (int ot = 0; ot < 4; ++ot)
      W2T[kk][ot] = ldfrag(pack, 16 + kk * 4 + ot, lane);

  float b1f[16];
#pragma unroll
  for (int j = 0; j < 8; ++j) {
    b1f[j]     = b1[q * 8 + j];
    b1f[8 + j] = b1[32 + q * 8 + j];
  }
  float b2v[4][4];                            // [ot][rg] = b2[ot*16+q*4+rg]
#pragma unroll
  for (int ot = 0; ot < 4; ++ot)
#pragma unroll
    for (int rg = 0; rg < 4; ++rg) b2v[ot][rg] = b2[ot * 16 + q * 4 + rg];
  const float al1 = a1p[0];
  const float al2 = a2p[0];

  const int start  = gofs[g], end = gofs[g + 1];
  const int g0     = g * 16;                  // first global node of group
  const int nbase  = (g / 6) * BNODE;         // bucket's first global node
  const int base16 = (g % 6) * 16;            // group's base dloc in bucket

  f4v acc[4];
#pragma unroll
  for (int ft = 0; ft < 4; ++ft) acc[ft] = (f4v){0.f, 0.f, 0.f, 0.f};

  for (int c0 = start; c0 < end; c0 += 32) {
#pragma unroll
    for (int tu = 0; tu < 2; ++tu) {
      const int e  = c0 + tu * 16 + r;
      const int ec = e < end ? e : end - 1;
      const int w  = ebuf2[ec];
      const int dl = w & 127;
      const int sn = w >> 7;
      const int dn = nbase + dl;
      if (q == 0) db[tu * 16 + r] = (e < end) ? (unsigned short)(dl - base16)
                                              : (unsigned short)0xFF;

      s8v fa = *(const s8v*)(F + (size_t)dn * 64 + q * 8);
      s8v fb = *(const s8v*)(F + (size_t)dn * 64 + 32 + q * 8);
      s8v ga = *(const s8v*)(G + (size_t)sn * 64 + q * 8);
      s8v gb = *(const s8v*)(G + (size_t)sn * 64 + 32 + q * 8);

      s8v p0, p1;
#pragma unroll
      for (int j = 0; j < 8; ++j) {
        float v = bf2f((unsigned short)fa[j]) + bf2f((unsigned short)ga[j]) + b1f[j];
        v = v >= 0.f ? v : al1 * v;
        p0[j] = (short)f2bf(v);
        float u = bf2f((unsigned short)fb[j]) + bf2f((unsigned short)gb[j]) + b1f[8 + j];
        u = u >= 0.f ? u : al1 * u;
        p1[j] = (short)f2bf(u);
      }

      // h2^T = prelu(W2^T @ h1^T + b2): C col=lane=edge, row=q*4+rg=feature
#pragma unroll
      for (int ot = 0; ot < 4; ++ot) {
        f4v c = {0.f, 0.f, 0.f, 0.f};
        c = MFMA16(W2T[0][ot], p0, c);
        c = MFMA16(W2T[1][ot], p1, c);
#pragma unroll
        for (int rg = 0; rg < 4; ++rg) {
          float v = c[rg] + b2v[ot][rg];
          v = v >= 0.f ? v : al2 * v;
          hb[(ot * 16 + q * 4 + rg) * H2STR + tu * 16 + r] = f2bf(v);
        }
      }
    }

    // S^T indicator A-frag: A[m=node=r][k=edge=q*8+j]
    s8v dv = *(const s8v*)(db + q * 8);
    s8v sA;
#pragma unroll
    for (int j = 0; j < 8; ++j)
      sA[j] = (short)(((int)(unsigned short)dv[j] == r) ? 0x3F80 : 0);

    // AGG += S^T @ H2 : B[k=edge=q*8+j][n=feat=ft*16+r]
#pragma unroll
    for (int ft = 0; ft < 4; ++ft) {
      s8v bf = *(const s8v*)(hb + (ft * 16 + r) * H2STR + q * 8);
      acc[ft] = MFMA16(sA, bf, acc[ft]);
    }
  }

  // flush: one plain store per (node, feature)
#pragma unroll
  for (int ft = 0; ft < 4; ++ft)
#pragma unroll
    for (int rg = 0; rg < 4; ++rg) {
      const int node = g0 + q * 4 + rg;
      if (node < NN) agg[(size_t)node * 64 + ft * 16 + r] = acc[ft][rg];
    }
}

// ---------------------------------------------------------------------------
// Node MLP: z = prelu(prelu(cat(x,agg) @ W3 + b3) @ W4 + b4, a_blk)
// ---------------------------------------------------------------------------
__global__ __launch_bounds__(256) void node_mlp_kernel(
    const float* __restrict__ x,
    const float* __restrict__ agg,
    const unsigned short* __restrict__ pack,
    const float* __restrict__ b3, const float* __restrict__ a3p,
    const float* __restrict__ b4, const float* __restrict__ ablkp,
    float* __restrict__ zout,
    float* __restrict__ part)
{
  const int lane = threadIdx.x & 63;
  const int wv   = threadIdx.x >> 6;
  const int q    = lane >> 4;
  const int r    = lane & 15;
  const int nw   = gridDim.x * 4;
  const int wid  = blockIdx.x * 4 + wv;

  s8v B3f[4][4];
  s8v B4f[2][4];
#pragma unroll
  for (int kk = 0; kk < 4; ++kk)
#pragma unroll
    for (int nt = 0; nt < 4; ++nt)
      B3f[kk][nt] = ldfrag(pack, 24 + kk * 4 + nt, lane);
#pragma unroll
  for (int kk = 0; kk < 2; ++kk)
#pragma unroll
    for (int nt = 0; nt < 4; ++nt)
      B4f[kk][nt] = ldfrag(pack, 40 + kk * 4 + nt, lane);

  float bias3[4], bias4[4];
#pragma unroll
  for (int nt = 0; nt < 4; ++nt) { bias3[nt] = b3[nt * 16 + r]; bias4[nt] = b4[nt * 16 + r]; }
  const float al3 = a3p[0];
  const float alb = ablkp[0];

  __shared__ __align__(16) unsigned short hbuf[4][16 * 72];
  unsigned short* hb = hbuf[wv];

  float bs[4] = {0.f, 0.f, 0.f, 0.f};
  float bq[4] = {0.f, 0.f, 0.f, 0.f};

  for (int t = wid; t < NN / 16; t += nw) {
    const int n = t * 16 + r;
    const f4v* xp = (const f4v*)(x + (size_t)n * 64);
    f4v x0 = xp[q * 2],     x1 = xp[q * 2 + 1];
    f4v x2 = xp[8 + q * 2], x3 = xp[8 + q * 2 + 1];
    const f4v* an4 = (const f4v*)(agg + (size_t)n * 64);
    f4v g0 = an4[q * 2],     g1 = an4[q * 2 + 1];
    f4v g2 = an4[8 + q * 2], g3 = an4[8 + q * 2 + 1];
    s8v a0, a1v, a2v, a3v;
#pragma unroll
    for (int j = 0; j < 4; ++j) {
      a0[j]      = (short)f2bf(x0[j]);
      a0[4 + j]  = (short)f2bf(x1[j]);
      a1v[j]     = (short)f2bf(x2[j]);
      a1v[4 + j] = (short)f2bf(x3[j]);
      a2v[j]     = (short)f2bf(g0[j]);
      a2v[4 + j] = (short)f2bf(g1[j]);
      a3v[j]     = (short)f2bf(g2[j]);
      a3v[4 + j] = (short)f2bf(g3[j]);
    }

    f4v acc[4];
#pragma unroll
    for (int nt = 0; nt < 4; ++nt) {
      f4v c = {0.f, 0.f, 0.f, 0.f};
      c = MFMA16(a0,  B3f[0][nt], c);
      c = MFMA16(a1v, B3f[1][nt], c);
      c = MFMA16(a2v, B3f[2][nt], c);
      c = MFMA16(a3v, B3f[3][nt], c);
      acc[nt] = c;
    }

#pragma unroll
    for (int nt = 0; nt < 4; ++nt)
#pragma unroll
      for (int rg = 0; rg < 4; ++rg) {
        float v = acc[nt][rg] + bias3[nt];
        v = v >= 0.f ? v : al3 * v;
        hb[(q * 4 + rg) * 72 + nt * 16 + r] = f2bf(v);
      }
    s8v p0 = *(const s8v*)(hb + r * 72 + q * 8);
    s8v p1 = *(const s8v*)(hb + r * 72 + 32 + q * 8);

    f4v acc2[4];
#pragma unroll
    for (int nt = 0; nt < 4; ++nt) {
      f4v c = {0.f, 0.f, 0.f, 0.f};
      c = MFMA16(p0, B4f[0][nt], c);
      c = MFMA16(p1, B4f[1][nt], c);
      acc2[nt] = c;
    }

#pragma unroll
    for (int nt = 0; nt < 4; ++nt)
#pragma unroll
      for (int rg = 0; rg < 4; ++rg) {
        float v = acc2[nt][rg] + bias4[nt];
        v = v >= 0.f ? v : alb * v;
        const int row = t * 16 + q * 4 + rg;
        zout[(size_t)row * 64 + nt * 16 + r] = v;
        bs[nt] += v;
        bq[nt] += v * v;
      }
  }

#pragma unroll
  for (int nt = 0; nt < 4; ++nt) {
    float s = bs[nt];
    s += __shfl_xor(s, 16, 64);
    s += __shfl_xor(s, 32, 64);
    float ss = bq[nt];
    ss += __shfl_xor(ss, 16, 64);
    ss += __shfl_xor(ss, 32, 64);
    if (q == 0) {
      atomicAdd(&part[nt * 16 + r], s);
      atomicAdd(&part[64 + nt * 16 + r], ss);
    }
  }
}

// ---------------------------------------------------------------------------
// BatchNorm finalize (in-place on d_out)
// ---------------------------------------------------------------------------
__global__ __launch_bounds__(256) void bn_kernel(
    float* __restrict__ out,
    const float* __restrict__ part,
    const float* __restrict__ gamma,
    const float* __restrict__ beta)
{
  const size_t i = (size_t)blockIdx.x * blockDim.x + threadIdx.x;
  if (i * 4 >= (size_t)NN * 64) return;
  float4 v = ((const float4*)out)[i];
  float e[4] = {v.x, v.y, v.z, v.w};
  const int f0 = (int)((i * 4) & 63);
  const float inv_n = 1.0f / (float)NN;
#pragma unroll
  for (int j = 0; j < 4; ++j) {
    const int f = f0 + j;
    const float mean = part[f] * inv_n;
    const float var  = part[64 + f] * inv_n - mean * mean;
    const float sc = rsqrtf(var + BN_EPS) * gamma[f];
    const float sh = beta[f] - mean * sc;
    e[j] = e[j] * sc + sh;
  }
  ((float4*)out)[i] = make_float4(e[0], e[1], e[2], e[3]);
}

extern "C" void kernel_launch(void* const* d_in, const int* in_sizes, int n_in,
                              void* d_out, int out_size, void* d_ws, size_t ws_size,
                              hipStream_t stream) {
  const float* x  = (const float*)d_in[0];
  const int* ei   = (const int*)d_in[1];
  const float* W1 = (const float*)d_in[2];
  const float* b1 = (const float*)d_in[3];
  const float* a1 = (const float*)d_in[4];
  const float* W2 = (const float*)d_in[5];
  const float* b2 = (const float*)d_in[6];
  const float* a2 = (const float*)d_in[7];
  const float* W3 = (const float*)d_in[8];
  const float* b3 = (const float*)d_in[9];
  const float* a3 = (const float*)d_in[10];
  const float* W4 = (const float*)d_in[11];
  const float* b4 = (const float*)d_in[12];
  const float* ab = (const float*)d_in[13];
  const float* gm = (const float*)d_in[14];
  const float* bt = (const float*)d_in[15];

  float* agg          = (float*)d_ws;                  // [NN*64] f32 (fully written)
  float* part         = agg + (size_t)NN * 64;         // [128] f32 (zeroed)
  unsigned short* F   = (unsigned short*)(part + 128); // [NN*64] bf16
  unsigned short* G   = F + (size_t)NN * 64;           // [NN*64] bf16
  int* hmat           = (int*)(G + (size_t)NN * 64);   // [NBKT*NBLK]
  int* total          = hmat + (size_t)NBKT * NBLK;    // [NBKT]
  int* boffs          = total + NBKT;                  // [NBKT+1] (+pad)
  int* gofs           = boffs + NBKT + 8;              // [NGRP+1] (+pad)
  int* ebuf           = gofs + NGRP + 8;               // [NE]
  int* ebuf2          = ebuf + NE;                     // [NE]
  unsigned short* pack = (unsigned short*)(ebuf2 + NE);// [NFRAG*64*8] bf16
  float* out          = (float*)d_out;

  const int* srcp = ei;        // edge_index[0] = src (x_j)
  const int* dstp = ei + NE;   // edge_index[1] = dst (x_i)

  hipMemsetAsync(part, 0, 128 * sizeof(float), stream);
  pack_kernel<<<dim3(1), dim3(256), 0, stream>>>(W1, W2, W3, W4, pack);
  pre_gemm_kernel<<<dim3(391), dim3(256), 0, stream>>>(x, pack, F, G);
  hist_kernel<<<dim3(NBLK), dim3(256), 0, stream>>>(dstp, hmat);
  scan_col_kernel<<<dim3((NBKT + 255) / 256), dim3(256), 0, stream>>>(hmat, total);
  scan_total_kernel<<<dim3(1), dim3(256), 0, stream>>>(total, boffs);
  scatter_kernel<<<dim3(NBLK), dim3(256), 0, stream>>>(srcp, dstp, hmat, boffs, ebuf);
  sort2_kernel<<<dim3(NBKT), dim3(256), 0, stream>>>(ebuf, boffs, ebuf2, gofs);
  edge_agg_kernel<<<dim3((NGRP + 3) / 4), dim3(256), 0, stream>>>(
      F, G, ebuf2, gofs, pack, b1, a1, b2, a2, agg);
  node_mlp_kernel<<<dim3(391), dim3(256), 0, stream>>>(
      x, agg, pack, b3, a3, b4, ab, out, part);
  bn_kernel<<<dim3(6250), dim3(256), 0, stream>>>(out, part, gm, bt);
}